// Round 5
// baseline (1660.150 us; speedup 1.0000x reference)
//
#include <hip/hip_runtime.h>
#include <math.h>

#define BB 128
#define TT 2048
#define II 128
#define UU 256
#define OO 128

// LDS-only barrier: orders LDS ops without draining vmcnt (global stores /
// prefetch loads stay in flight). sched_barrier(0) pins ordering (rule 18).
__device__ __forceinline__ void bar_lds() {
    __builtin_amdgcn_sched_barrier(0);
    asm volatile("s_waitcnt lgkmcnt(0)" ::: "memory");
    __builtin_amdgcn_s_barrier();
    __builtin_amdgcn_sched_barrier(0);
}

__device__ __forceinline__ void fma4(float4& a, const float4 w, const float4 h) {
    a.x = fmaf(w.x, h.x, a.x);
    a.y = fmaf(w.y, h.y, a.y);
    a.z = fmaf(w.z, h.z, a.z);
    a.w = fmaf(w.w, h.w, a.w);
}

// DPP cross-lane exchanges (pure VALU, no LDS pipe):
__device__ __forceinline__ float dpp_xor1(float x) {   // quad_perm [1,0,3,2]
    return __int_as_float(__builtin_amdgcn_mov_dpp(__float_as_int(x), 0xB1, 0xF, 0xF, true));
}
__device__ __forceinline__ float dpp_xor2(float x) {   // quad_perm [2,3,0,1]
    return __int_as_float(__builtin_amdgcn_mov_dpp(__float_as_int(x), 0x4E, 0xF, 0xF, true));
}
__device__ __forceinline__ float dpp_xor8(float x) {   // row_ror:8 (xor8 in 16)
    return __int_as_float(__builtin_amdgcn_mov_dpp(__float_as_int(x), 0x128, 0xF, 0xF, true));
}
__device__ __forceinline__ float swz_xor4(float x) {   // ds_swizzle xor4
    return __int_as_float(__builtin_amdgcn_ds_swizzle(__float_as_int(x), 0x101F));
}

// 4-row value-splitting butterfly. CONTRACT: lane ends with the FULL sum of
// row (tid & 3) of this group (after xor over lane bits 0,1,3). s0..s3 are
// this lane's k-chunk partials for rows u0+0..3.
__device__ __forceinline__ float reduce4(float s0, float s1, float s2, float s3,
                                         int tid) {
    const bool e1 = (tid & 1), e2 = (tid & 2);
    float z0 = e1 ? s0 : s1;
    float z1 = e1 ? s2 : s3;
    float A0 = (e1 ? s1 : s0) + dpp_xor1(z0);   // row bit0
    float A1 = (e1 ? s3 : s2) + dpp_xor1(z1);   // row 2+bit0
    float z2 = e2 ? A0 : A1;
    float C = (e2 ? A1 : A0) + dpp_xor2(z2);    // row (tid&3)
    return C + dpp_xor8(C);                      // + other k-half (bit 3)
}

// ---------------- Kernel 1: input projection ----------------
// xp[row,u] = x[row,:] . W_ih[u,:] + b_ih[u] + b_hh[u]
// 512 thr: kk = lane bits {0,1,3} -> 8 chunks of 16 floats (K=128);
// G = 64 groups own 4 u each. Per row: 4 ds_read_b128 feed 16 fma4.
__global__ __launch_bounds__(512, 2) void k_inproj(
    const float* __restrict__ x, const float* __restrict__ Wih,
    const float* __restrict__ bih, const float* __restrict__ bhh,
    float* __restrict__ xp)
{
    __shared__ __align__(16) float xs[64 * 160];   // 64 rows x 8 chunks x 20
    const int tid = threadIdx.x;
    const int kk = (tid & 3) | ((tid >> 1) & 4);   // bits 0,1,3
    const int G  = ((tid >> 2) & 1) | ((tid >> 4) << 1);   // 0..63
    const int u0 = G * 4;
    float4 w[4][4];
    #pragma unroll
    for (int r = 0; r < 4; ++r)
        #pragma unroll
        for (int j = 0; j < 4; ++j)
            w[r][j] = *reinterpret_cast<const float4*>(
                &Wih[(size_t)(u0 + r) * II + kk * 16 + j * 4]);
    const int r3 = tid & 3;                        // matches reduce4 contract
    const int uw = u0 + r3;
    const float bias = bih[uw] + bhh[uw];
    const bool writer = (tid & 8) == 0;
    const int ntiles = (BB * TT) / 64;             // 4096
    for (int tile = blockIdx.x; tile < ntiles; tile += gridDim.x) {
        const size_t rowbase = (size_t)tile * 64;
        const float4* xg = reinterpret_cast<const float4*>(x + rowbase * II);
        #pragma unroll
        for (int i = 0; i < 4; ++i) {
            int v = tid + i * 512;                 // 0..2047 float4s
            int row = v >> 5, q = v & 31;
            float4 val = xg[v];
            *reinterpret_cast<float4*>(&xs[row * 160 + (q >> 2) * 20 + (q & 3) * 4]) = val;
        }
        __syncthreads();
        for (int r = 0; r < 64; ++r) {
            const float4* hrow = reinterpret_cast<const float4*>(&xs[r * 160 + kk * 20]);
            float4 a0 = {0,0,0,0}, a1 = {0,0,0,0}, a2 = {0,0,0,0}, a3 = {0,0,0,0};
            #pragma unroll
            for (int j = 0; j < 4; ++j) {
                float4 hv = hrow[j];
                fma4(a0, w[0][j], hv); fma4(a1, w[1][j], hv);
                fma4(a2, w[2][j], hv); fma4(a3, w[3][j], hv);
            }
            float s0 = (a0.x + a0.y) + (a0.z + a0.w);
            float s1 = (a1.x + a1.y) + (a1.z + a1.w);
            float s2 = (a2.x + a2.y) + (a2.z + a2.w);
            float s3 = (a3.x + a3.y) + (a3.z + a3.w);
            float D = reduce4(s0, s1, s2, s3, tid);
            if (writer) xp[(rowbase + r) * UU + uw] = D + bias;
        }
        __syncthreads();
    }
}

// ---------------- Kernel 2: serial recurrence ----------------
// 1 block/batch, 1024 thr (16 waves = 4/SIMD for latency hiding).
// kk = lane bits {0,1,3} -> 8 chunks of 32 floats (stride 36, conflict-free,
// measured 0 conflicts). G = bits {2,4..9} -> 128 groups x 2 u rows.
// Reduce: 1 value-split stage (bit0 -> row) + DPP xor2 + DPP xor8.
// Each u has 4 finalized copies (bits 1,3): (b1=0,b3=0) writes masked h to
// LDS; (b1=1,b3=0) writes h_raw to global. ONE barrier per step.
__global__ __launch_bounds__(1024, 4) void k_rnn(
    const float* __restrict__ Whh, float* __restrict__ xph)
{
    __shared__ __align__(16) float hc[2 * 288];    // 2 bufs x 8 chunks x 36
    const int tid = threadIdx.x;
    const int kk = (tid & 3) | ((tid >> 1) & 4);   // bits 0,1,3
    const int G  = ((tid >> 2) & 1) | ((tid >> 4) << 1);   // 0..127
    const int u0 = G * 2;
    float4 w[2][8];
    #pragma unroll
    for (int r = 0; r < 2; ++r)
        #pragma unroll
        for (int j = 0; j < 8; ++j)
            w[r][j] = *reinterpret_cast<const float4*>(
                &Whh[(size_t)(u0 + r) * UU + kk * 32 + j * 4]);
    const int uw = u0 + (tid & 1);                 // u this lane finalizes
    const bool ldswr  = (tid & 2) == 0 && (tid & 8) == 0;
    const bool globwr = (tid & 2) != 0 && (tid & 8) == 0;
    const bool kill = (uw == 3) || (uw == 7);
    const int wr_off = (uw >> 5) * 36 + (uw & 31); // LDS h slot for uw

    if (tid < 144) *reinterpret_cast<float4*>(&hc[tid * 4]) = (float4){0,0,0,0};
    __syncthreads();

    float* rowp = xph + (size_t)blockIdx.x * (size_t)TT * UU;
    float xpv = rowp[uw];
    float xpn = rowp[UU + uw];

    auto step = [&](int t, int p) {
        int tn = t + 2; tn = (tn < TT) ? tn : (TT - 1);      // branchless clamp
        float xpn2 = rowp[(size_t)tn * UU + uw];
        const float4* hb = reinterpret_cast<const float4*>(&hc[p * 288 + kk * 36]);
        float4 a0 = {0,0,0,0}, a1 = {0,0,0,0};
        #pragma unroll
        for (int j = 0; j < 8; ++j) {
            float4 hv = hb[j];
            fma4(a0, w[0][j], hv); fma4(a1, w[1][j], hv);
        }
        float s0 = (a0.x + a0.y) + (a0.z + a0.w);
        float s1 = (a1.x + a1.y) + (a1.z + a1.w);
        // stage 1 (xor1): resolve row bit0 by value-splitting
        const bool e1 = (tid & 1);
        float z = e1 ? s0 : s1;
        float A = (e1 ? s1 : s0) + dpp_xor1(z);    // row u0+(tid&1), 2 chunks
        A += dpp_xor2(A);                          // + bit1 chunks
        A += dpp_xor8(A);                          // + bit3 chunks -> full sum
        float s = A + xpv;
        float hr = 1.0f - 2.0f / (__expf(2.0f * s) + 1.0f);
        if (globwr) {
            rowp[(size_t)t * UU + uw] = hr;                  // h_raw
        } else if (ldswr) {
            hc[(p ^ 1) * 288 + wr_off] = kill ? 0.f : hr;    // masked carry
        }
        bar_lds();
        xpv = xpn; xpn = xpn2;
    };
    for (int t = 0; t < TT; t += 2) { step(t, 0); step(t + 1, 1); }
}

// ---------------- Kernel 3: readout + mask fix-up ----------------
// 512 thr: kk = tid&15 -> 16 chunks of 16 floats (K=256, stride 20);
// G = 32 groups own 4 o each. Reduce: quad,quad DPP + ror8 + ds_swizzle xor4.
__global__ __launch_bounds__(512, 2) void k_readout(
    const float* __restrict__ Wfc, const float* __restrict__ bfc,
    float* __restrict__ hraw, float* __restrict__ outR)
{
    __shared__ __align__(16) float hs[32 * 320];   // 32 rows x 16 chunks x 20
    const int tid = threadIdx.x;
    const int kk = tid & 15;
    const int G  = tid >> 4;                       // 0..31
    const int o0 = G * 4;
    float4 w[4][4];
    #pragma unroll
    for (int r = 0; r < 4; ++r)
        #pragma unroll
        for (int j = 0; j < 4; ++j)
            w[r][j] = *reinterpret_cast<const float4*>(
                &Wfc[(size_t)(o0 + r) * UU + kk * 16 + j * 4]);
    const int ow = o0 + (tid & 3);                 // matches reduce contract
    const float bias = bfc[ow];
    const bool writer = (tid & 12) == 0;
    const int ntiles = (BB * TT) / 32;             // 8192
    for (int tile = blockIdx.x; tile < ntiles; tile += gridDim.x) {
        const size_t rowbase = (size_t)tile * 32;
        const float4* hg = reinterpret_cast<const float4*>(hraw + rowbase * UU);
        #pragma unroll
        for (int i = 0; i < 4; ++i) {
            int v = tid + i * 512;                 // 0..2047 float4s
            int row = v >> 6, q = v & 63;
            float4 val = hg[v];
            *reinterpret_cast<float4*>(&hs[row * 320 + (q >> 2) * 20 + (q & 3) * 4]) = val;
        }
        __syncthreads();
        // raw values staged: zero killed units in the global hs output
        if (tid < 64) {
            int r = tid >> 1, c = (tid & 1) ? 7 : 3;
            hraw[(rowbase + r) * UU + c] = 0.f;
        }
        for (int r = 0; r < 32; ++r) {
            const float4* hrow = reinterpret_cast<const float4*>(&hs[r * 320 + kk * 20]);
            float4 a0 = {0,0,0,0}, a1 = {0,0,0,0}, a2 = {0,0,0,0}, a3 = {0,0,0,0};
            #pragma unroll
            for (int j = 0; j < 4; ++j) {
                float4 hv = hrow[j];
                fma4(a0, w[0][j], hv); fma4(a1, w[1][j], hv);
                fma4(a2, w[2][j], hv); fma4(a3, w[3][j], hv);
            }
            float s0 = (a0.x + a0.y) + (a0.z + a0.w);
            float s1 = (a1.x + a1.y) + (a1.z + a1.w);
            float s2 = (a2.x + a2.y) + (a2.z + a2.w);
            float s3 = (a3.x + a3.y) + (a3.z + a3.w);
            // stage1/2: resolve row bits 0,1 (same as reduce4, sans xor8)
            const bool e1 = (tid & 1), e2 = (tid & 2);
            float z0 = e1 ? s0 : s1;
            float z1 = e1 ? s2 : s3;
            float A0 = (e1 ? s1 : s0) + dpp_xor1(z0);
            float A1 = (e1 ? s3 : s2) + dpp_xor1(z1);
            float z2 = e2 ? A0 : A1;
            float C = (e2 ? A1 : A0) + dpp_xor2(z2);
            float C2 = C + dpp_xor8(C);            // + bit3 half
            float D  = C2 + swz_xor4(C2);          // + bit2 half (all 16 kk)
            if (writer) outR[(rowbase + r) * OO + ow] = D + bias;
        }
        __syncthreads();
    }
}

extern "C" void kernel_launch(void* const* d_in, const int* in_sizes, int n_in,
                              void* d_out, int out_size, void* d_ws, size_t ws_size,
                              hipStream_t stream) {
    const float* x   = (const float*)d_in[0];
    const float* Wih = (const float*)d_in[1];
    const float* Whh = (const float*)d_in[2];
    const float* bih = (const float*)d_in[3];
    const float* bhh = (const float*)d_in[4];
    const float* Wfc = (const float*)d_in[5];
    const float* bfc = (const float*)d_in[6];
    float* outR = (float*)d_out;                       // readouts [B,T,O]
    float* outH = outR + (size_t)BB * TT * OO;         // hs       [B,T,U]

    k_inproj<<<512, 512, 0, stream>>>(x, Wih, bih, bhh, outH);
    k_rnn<<<128, 1024, 0, stream>>>(Whh, outH);
    k_readout<<<512, 512, 0, stream>>>(Wfc, bfc, outH, outR);
}